// Round 7
// baseline (258.634 us; speedup 1.0000x reference)
//
#include <hip/hip_runtime.h>
#include <stdint.h>
#include <math.h>

#define B_DIM 32
#define T_DIM 1024
#define C_DIM 768
#define WT    64                    // per-wave tile
#define NT    (T_DIM / WT)          // 16
#define NTRI  (NT * (NT + 1) / 2)   // 136 triangular 64x64 tasks per batch
#define NBLK  (NTRI / 4)            // 34 blocks per batch (4 waves = 4 tasks)
#define KITER (C_DIM / 32)          // 24

typedef float f32x4 __attribute__((ext_vector_type(4)));

typedef __attribute__((address_space(1))) void gvoid_t;
typedef __attribute__((address_space(3))) void lvoid_t;

// One wave per row: compute 1/||x||_2 and store normalized row as fp8 e4m3.
// Row layout: 768 fp8 bytes = 192 dwords; lane L owns dword L, L+64, L+128
// (elements 4L..4L+3 etc.) -> coalesced dword stores.
__global__ __launch_bounds__(256) void normalize_rows_fp8(const float* __restrict__ x,
                                                          uint32_t* __restrict__ m) {
    const int row  = blockIdx.x * 4 + (threadIdx.x >> 6);
    const int lane = threadIdx.x & 63;
    const float4* xr = (const float4*)(x + (size_t)row * C_DIM);
    float4 v0 = xr[lane];
    float4 v1 = xr[lane + 64];
    float4 v2 = xr[lane + 128];
    float ss = v0.x*v0.x + v0.y*v0.y + v0.z*v0.z + v0.w*v0.w
             + v1.x*v1.x + v1.y*v1.y + v1.z*v1.z + v1.w*v1.w
             + v2.x*v2.x + v2.y*v2.y + v2.z*v2.z + v2.w*v2.w;
    #pragma unroll
    for (int off = 32; off > 0; off >>= 1)
        ss += __shfl_xor(ss, off, 64);
    const float rs = rsqrtf(ss);
    uint32_t* mr = m + (size_t)row * (C_DIM / 4);
    int p;
    p = __builtin_amdgcn_cvt_pk_fp8_f32(v0.x * rs, v0.y * rs, 0, false);
    p = __builtin_amdgcn_cvt_pk_fp8_f32(v0.z * rs, v0.w * rs, p, true);
    mr[lane] = (uint32_t)p;
    p = __builtin_amdgcn_cvt_pk_fp8_f32(v1.x * rs, v1.y * rs, 0, false);
    p = __builtin_amdgcn_cvt_pk_fp8_f32(v1.z * rs, v1.w * rs, p, true);
    mr[lane + 64] = (uint32_t)p;
    p = __builtin_amdgcn_cvt_pk_fp8_f32(v2.x * rs, v2.y * rs, 0, false);
    p = __builtin_amdgcn_cvt_pk_fp8_f32(v2.z * rs, v2.w * rs, p, true);
    mr[lane + 128] = (uint32_t)p;
}

// Batched symmetric NT GEMM on fp8 e4m3, BARRIER-FREE:
//   out[b,i,j] = 1 - sum_k M[b,i,k]*M[b,j,k]
// Each WAVE owns one triangular 64x64 tile and a PRIVATE double-buffered LDS
// ring (producer == consumer), so LDS validity is guaranteed by the wave's own
// vmcnt -- there is no __syncthreads in the K-loop at all. Waves free-run;
// ~17-20 independent waves/CU hide each other's stage latency. Counted
// vmcnt(4) keeps the next K-slice's DMA in flight during compute (never
// drains to 0 mid-loop).
//
// (s_setprio removed this attempt: only element never exercised in this
// structure on this problem; shrinking novelty surface after two opaque
// container failures.)
//
// LDS half-swizzle (16B granule): LDS row r's half h holds content col
// h ^ ((r>>2)&1) -- realized by pre-swizzling the GLOBAL source column
// (global_load_lds writes linearly); ds_reads XOR the same bit. Breaks the
// stride-32B ds_read_b64 bank aliasing to 2-way (free).
//
// K-accumulation order per output element is identical to the 128-tile
// version (k=0..767 in 32-steps of 16x16x32 MFMA) -> absmax must stay
// bit-identical (0.01403856).
__global__ __launch_bounds__(256) void gemm_nt_sym_fp8_wave(const uint8_t* __restrict__ M,
                                                            float* __restrict__ out) {
    // [wave][buf][A|B][64 rows * 32 B] = 4 * 2 * 2 * 2 KB = 32 KB.
    __shared__ uint8_t lds[4][2][2][WT * 32];

    const int b  = blockIdx.x & 31;    // batch fastest -> batch pinned to XCD (b&7)
    const int tg = blockIdx.x >> 5;    // task group 0..33
    const int tid  = threadIdx.x;
    const int wave = tid >> 6;
    const int lane = tid & 63;
    const int quad = lane >> 4;
    const int l16  = lane & 15;

    // Unrank triangular task t -> (ti <= tj), 16x16 tile grid.
    const int t = tg * 4 + wave;       // 0..135
    int tj = (int)((sqrtf(8.0f * (float)t + 1.0f) - 1.0f) * 0.5f);
    if (tj * (tj + 1) / 2 > t) --tj;
    if ((tj + 1) * (tj + 2) / 2 <= t) ++tj;
    const int ti = t - tj * (tj + 1) / 2;

    const uint8_t* Mb = M + (size_t)b * T_DIM * C_DIM;

    // Staging: per buffer, A-chunk = 2 KB = 2 DMA instrs of 1 KB (32 rows,
    // 32 B/row, 2 lanes/row); same for B. LDS dest is wave-uniform base +
    // lane*16 (HW rule); content swizzle realized via the global source col.
    // LDS row for lane L in a chunk = chunk*32 + (L>>1); swizzle bit =
    // ((row>>2)&1) = ((L>>3)&1) (chunk*32 contributes 0 to bit 2).
    const int srow = lane >> 1;
    const int scol = ((lane & 1) * 16) ^ (((lane >> 3) & 1) << 4);
    const uint8_t* gA = Mb + (size_t)(ti * WT + srow) * C_DIM + scol;
    const uint8_t* gB = Mb + (size_t)(tj * WT + srow) * C_DIM + scol;

#define STAGE(buf_, koff_)                                                                                   \
    do {                                                                                                     \
        __builtin_amdgcn_global_load_lds((gvoid_t*)(gA + (koff_)),               (lvoid_t*)&lds[wave][buf_][0][0],    16, 0, 0); \
        __builtin_amdgcn_global_load_lds((gvoid_t*)(gA + (koff_) + 32 * C_DIM),  (lvoid_t*)&lds[wave][buf_][0][1024], 16, 0, 0); \
        __builtin_amdgcn_global_load_lds((gvoid_t*)(gB + (koff_)),               (lvoid_t*)&lds[wave][buf_][1][0],    16, 0, 0); \
        __builtin_amdgcn_global_load_lds((gvoid_t*)(gB + (koff_) + 32 * C_DIM),  (lvoid_t*)&lds[wave][buf_][1][1024], 16, 0, 0); \
    } while (0)

    // Swizzled ds_read fragment offsets: row = ii*16 + l16, slot = quad*8;
    // swizzle bit = ((row>>2)&1) = ((l16>>2)&1).
    const int sw = ((l16 >> 2) & 1) << 4;
    int offF[4];
    #pragma unroll
    for (int ii = 0; ii < 4; ++ii)
        offF[ii] = (ii * 16 + l16) * 32 + ((quad * 8) ^ sw);

    f32x4 acc[4][4];
    #pragma unroll
    for (int i = 0; i < 4; ++i)
        #pragma unroll
        for (int j = 0; j < 4; ++j)
            acc[i][j] = (f32x4){0.f, 0.f, 0.f, 0.f};

    // Prologue: stage K-slice 0 into buffer 0.
    STAGE(0, 0);

    for (int it = 0; it < KITER; ++it) {
        const int cur = it & 1;
        // Iteration fence: keep previous iteration's ds_reads (of buf cur^1)
        // ahead of the DMA that overwrites buf cur^1 below.
        __builtin_amdgcn_sched_barrier(0);
        if (it + 1 < KITER) {
            STAGE(cur ^ 1, (it + 1) * 32);
            // Outstanding: stage(it) 4 + stage(it+1) 4 -> wait for oldest 4.
            asm volatile("s_waitcnt vmcnt(4)" ::: "memory");
        } else {
            asm volatile("s_waitcnt vmcnt(0)" ::: "memory");
        }
        __builtin_amdgcn_sched_barrier(0);

        long af[4], bfr[4];
        #pragma unroll
        for (int ii = 0; ii < 4; ++ii) {
            af[ii]  = *(const long*)&lds[wave][cur][0][offF[ii]];
            bfr[ii] = *(const long*)&lds[wave][cur][1][offF[ii]];
        }
        #pragma unroll
        for (int ii = 0; ii < 4; ++ii)
            #pragma unroll
            for (int jj = 0; jj < 4; ++jj)
                acc[ii][jj] = __builtin_amdgcn_mfma_f32_16x16x32_fp8_fp8(af[ii], bfr[jj], acc[ii][jj], 0, 0, 0);
    }
#undef STAGE

    // Epilogue. C/D layout: col = lane&15, row = quad*4 + reg. out = 1 - acc.
    float* outb = out + (size_t)b * T_DIM * T_DIM;
    #pragma unroll
    for (int ii = 0; ii < 4; ++ii) {
        const int rowbase = ti * WT + ii * 16 + quad * 4;
        #pragma unroll
        for (int jj = 0; jj < 4; ++jj) {
            const int col = tj * WT + jj * 16 + l16;
            #pragma unroll
            for (int r = 0; r < 4; ++r)
                outb[(size_t)(rowbase + r) * T_DIM + col] = 1.0f - acc[ii][jj][r];
        }
    }
    if (ti != tj) {
        // Mirror tile: each lane's 4 acc values share one col and 4 consecutive
        // rows -> one aligned f32x4 store; 4 quads of same l16 cover a 64B line.
        #pragma unroll
        for (int ii = 0; ii < 4; ++ii) {
            const int rowbase = ti * WT + ii * 16 + quad * 4;
            #pragma unroll
            for (int jj = 0; jj < 4; ++jj) {
                const int col = tj * WT + jj * 16 + l16;
                f32x4 v;
                v[0] = 1.0f - acc[ii][jj][0];
                v[1] = 1.0f - acc[ii][jj][1];
                v[2] = 1.0f - acc[ii][jj][2];
                v[3] = 1.0f - acc[ii][jj][3];
                *(f32x4*)(outb + (size_t)col * T_DIM + rowbase) = v;
            }
        }
    }
}

extern "C" void kernel_launch(void* const* d_in, const int* in_sizes, int n_in,
                              void* d_out, int out_size, void* d_ws, size_t ws_size,
                              hipStream_t stream) {
    const float* x = (const float*)d_in[0];
    float* out = (float*)d_out;
    uint32_t* metric = (uint32_t*)d_ws;  // 32768 x 768 fp8 = 24 MiB

    normalize_rows_fp8<<<dim3((B_DIM * T_DIM) / 4), dim3(256), 0, stream>>>(x, metric);
    // 1088 blocks = 34 task-groups x 32 batches, batch-fastest: all of batch
    // b's blocks share XCD (b&7); each wave owns one triangular 64x64 tile.
    gemm_nt_sym_fp8_wave<<<dim3(NBLK * B_DIM), dim3(256), 0, stream>>>((const uint8_t*)metric, out);
}

// Round 8
// 241.309 us; speedup vs baseline: 1.0718x; 1.0718x over previous
//
#include <hip/hip_runtime.h>
#include <hip/hip_bf16.h>
#include <stdint.h>
#include <math.h>

#define B_DIM 32
#define T_DIM 1024
#define C_DIM 768
#define NTILE 8                 // T_DIM / 128
#define NTRI  36                // NTILE*(NTILE+1)/2
#define KITER (C_DIM / 64)      // 12 iterations of BK=64

typedef float f32x4 __attribute__((ext_vector_type(4)));

typedef __attribute__((address_space(1))) void gvoid_t;
typedef __attribute__((address_space(3))) void lvoid_t;

// One wave per row: compute 1/||x||_2 and store normalized row as fp8 e4m3.
// Row layout: 768 fp8 bytes = 192 dwords; lane L owns dword L, L+64, L+128
// (elements 4L..4L+3 etc.) -> coalesced dword stores.
__global__ __launch_bounds__(256) void normalize_rows_fp8(const float* __restrict__ x,
                                                          uint32_t* __restrict__ m) {
    const int row  = blockIdx.x * 4 + (threadIdx.x >> 6);
    const int lane = threadIdx.x & 63;
    const float4* xr = (const float4*)(x + (size_t)row * C_DIM);
    float4 v0 = xr[lane];
    float4 v1 = xr[lane + 64];
    float4 v2 = xr[lane + 128];
    float ss = v0.x*v0.x + v0.y*v0.y + v0.z*v0.z + v0.w*v0.w
             + v1.x*v1.x + v1.y*v1.y + v1.z*v1.z + v1.w*v1.w
             + v2.x*v2.x + v2.y*v2.y + v2.z*v2.z + v2.w*v2.w;
    #pragma unroll
    for (int off = 32; off > 0; off >>= 1)
        ss += __shfl_xor(ss, off, 64);
    const float rs = rsqrtf(ss);
    uint32_t* mr = m + (size_t)row * (C_DIM / 4);
    int p;
    p = __builtin_amdgcn_cvt_pk_fp8_f32(v0.x * rs, v0.y * rs, 0, false);
    p = __builtin_amdgcn_cvt_pk_fp8_f32(v0.z * rs, v0.w * rs, p, true);
    mr[lane] = (uint32_t)p;
    p = __builtin_amdgcn_cvt_pk_fp8_f32(v1.x * rs, v1.y * rs, 0, false);
    p = __builtin_amdgcn_cvt_pk_fp8_f32(v1.z * rs, v1.w * rs, p, true);
    mr[lane + 64] = (uint32_t)p;
    p = __builtin_amdgcn_cvt_pk_fp8_f32(v2.x * rs, v2.y * rs, 0, false);
    p = __builtin_amdgcn_cvt_pk_fp8_f32(v2.z * rs, v2.w * rs, p, true);
    mr[lane + 128] = (uint32_t)p;
}

// Batched symmetric NT GEMM on fp8 e4m3: out[b,i,j] = 1 - sum_k M[b,i,k]*M[b,j,k].
// Upper-triangular 128x128 tiles only; off-diagonal mirrored via transposed
// f32x4 stores. Batch-fastest flat grid pins each batch's 36 blocks to one XCD.
//
// IDENTICAL K-loop to the verified 244.0-us BK=64 version (R4). The ONE change
// this round: ALL epilogue stores are nontemporal. Mechanism: per XCD the
// metric working set (4 batch panels x 768 KB = 3 MB) fits the 4 MB L2, but
// the epilogue streams 17 MB/XCD of never-reread output through that same L2,
// evicting the panels; evicted metric reads fall from L2 (34.5 TB/s) to
// L3/HBM. NT stores keep the output stream out of L2.
__global__ __launch_bounds__(256) void gemm_nt_sym_fp8(const uint8_t* __restrict__ M,
                                                       float* __restrict__ out) {
    // [buf][ksub][128*32] fp8: 4 KB per sub-block, 16 KB per matrix, 32 KB total.
    __shared__ uint8_t As[2][2][128 * 32];
    __shared__ uint8_t Bs[2][2][128 * 32];

    const int b   = blockIdx.x & 31;   // batch fastest -> batch pinned to XCD (b&7)
    const int idx = blockIdx.x >> 5;   // triangular tile index, 0..35
    int tj = (int)((sqrtf(8.0f * (float)idx + 1.0f) - 1.0f) * 0.5f);
    if (tj * (tj + 1) / 2 > idx) --tj;
    const int ti = idx - tj * (tj + 1) / 2;   // ti <= tj

    const int tid  = threadIdx.x;
    const int wave = tid >> 6;
    const int lane = tid & 63;
    const int quad = lane >> 4;
    const int l16  = lane & 15;
    const int wi = wave >> 1;
    const int wj = wave & 1;

    const uint8_t* Mb = M + (size_t)b * T_DIM * C_DIM;

    // Staging: each sub-block = 4 chunks of 1 KB; wave w stages chunk w.
    // Chunk rows: w*32 .. w*32+31 (32 B/row in the sub-block, 2 lanes per row).
    // LDS dest = wave-uniform chunk base + lane*16 (HW rule); the content
    // permutation is realized by XOR-ing the global source column.
    const int srow = wave * 32 + (lane >> 1);
    const int scol = ((lane & 1) * 16) ^ ((((srow >> 2) & 1)) << 4);

    const uint8_t* gA = Mb + (size_t)(ti * 128 + srow) * C_DIM + scol;
    const uint8_t* gB = Mb + (size_t)(tj * 128 + srow) * C_DIM + scol;
    const int cbase = wave * 1024;

    // Swizzled ds_read fragment offsets within a 4 KB sub-block:
    // row = w*64 + ii*16 + l16, slot = quad*8, sw = ((l16>>2)&1)<<4.
    const int sw = ((l16 >> 2) & 1) << 4;
    int offA[4], offB[4];
    #pragma unroll
    for (int ii = 0; ii < 4; ++ii) {
        offA[ii] = (wi * 64 + ii * 16 + l16) * 32 + ((quad * 8) ^ sw);
        offB[ii] = (wj * 64 + ii * 16 + l16) * 32 + ((quad * 8) ^ sw);
    }

    f32x4 acc[4][4];
    #pragma unroll
    for (int i = 0; i < 4; ++i)
        #pragma unroll
        for (int j = 0; j < 4; ++j)
            acc[i][j] = (f32x4){0.f, 0.f, 0.f, 0.f};

    // Prologue: stage K-slice 0 (both 32B sub-slices) into buffer 0.
    #pragma unroll
    for (int s = 0; s < 2; ++s) {
        __builtin_amdgcn_global_load_lds((gvoid_t*)(gA + s * 32), (lvoid_t*)&As[0][s][cbase], 16, 0, 0);
        __builtin_amdgcn_global_load_lds((gvoid_t*)(gB + s * 32), (lvoid_t*)&Bs[0][s][cbase], 16, 0, 0);
    }

    for (int it = 0; it < KITER; ++it) {
        const int cur = it & 1;
        // Drains this wave's outstanding stage DMA (vmcnt(0) before barrier) and
        // guarantees all waves finished reading buf[cur^1] from iter it-1.
        __syncthreads();
        if (it + 1 < KITER) {
            const int k0 = (it + 1) * 64;   // byte offset along K
            const int nxt = cur ^ 1;
            #pragma unroll
            for (int s = 0; s < 2; ++s) {
                __builtin_amdgcn_global_load_lds((gvoid_t*)(gA + k0 + s * 32), (lvoid_t*)&As[nxt][s][cbase], 16, 0, 0);
                __builtin_amdgcn_global_load_lds((gvoid_t*)(gB + k0 + s * 32), (lvoid_t*)&Bs[nxt][s][cbase], 16, 0, 0);
            }
        }

        // Two sub-slices per barrier: {ds_read x8, 16 MFMA} x2. K-summation
        // order per output element is identical to the BK=32 version.
        #pragma unroll
        for (int s = 0; s < 2; ++s) {
            long af[4], bfr[4];
            #pragma unroll
            for (int ii = 0; ii < 4; ++ii) {
                af[ii]  = *(const long*)&As[cur][s][offA[ii]];
                bfr[ii] = *(const long*)&Bs[cur][s][offB[ii]];
            }
            #pragma unroll
            for (int ii = 0; ii < 4; ++ii)
                #pragma unroll
                for (int jj = 0; jj < 4; ++jj)
                    acc[ii][jj] = __builtin_amdgcn_mfma_f32_16x16x32_fp8_fp8(af[ii], bfr[jj], acc[ii][jj], 0, 0, 0);
        }
    }

    // Epilogue. C/D layout: col = lane&15, row = quad*4 + reg. out = 1 - acc.
    // All stores NONTEMPORAL (output is never re-read; keep it out of L2).
    float* outb = out + (size_t)b * T_DIM * T_DIM;
    #pragma unroll
    for (int ii = 0; ii < 4; ++ii) {
        const int rowbase = ti * 128 + wi * 64 + ii * 16 + quad * 4;
        #pragma unroll
        for (int jj = 0; jj < 4; ++jj) {
            const int col = tj * 128 + wj * 64 + jj * 16 + l16;
            #pragma unroll
            for (int r = 0; r < 4; ++r)
                __builtin_nontemporal_store(1.0f - acc[ii][jj][r],
                                            &outb[(size_t)(rowbase + r) * T_DIM + col]);
        }
    }
    if (ti != tj) {
        // Mirror tile: each lane's 4 acc values share one col and 4 consecutive
        // rows -> one aligned f32x4 store; 4 quads of same l16 cover a 64B line.
        #pragma unroll
        for (int ii = 0; ii < 4; ++ii) {
            const int rowbase = ti * 128 + wi * 64 + ii * 16 + quad * 4;
            #pragma unroll
            for (int jj = 0; jj < 4; ++jj) {
                const int col = tj * 128 + wj * 64 + jj * 16 + l16;
                f32x4 v;
                v[0] = 1.0f - acc[ii][jj][0];
                v[1] = 1.0f - acc[ii][jj][1];
                v[2] = 1.0f - acc[ii][jj][2];
                v[3] = 1.0f - acc[ii][jj][3];
                __builtin_nontemporal_store(v, (f32x4*)(outb + (size_t)col * T_DIM + rowbase));
            }
        }
    }
}

extern "C" void kernel_launch(void* const* d_in, const int* in_sizes, int n_in,
                              void* d_out, int out_size, void* d_ws, size_t ws_size,
                              hipStream_t stream) {
    const float* x = (const float*)d_in[0];
    float* out = (float*)d_out;
    uint32_t* metric = (uint32_t*)d_ws;  // 32768 x 768 fp8 = 24 MiB

    normalize_rows_fp8<<<dim3((B_DIM * T_DIM) / 4), dim3(256), 0, stream>>>(x, metric);
    // 1152 blocks, batch-fastest: all 36 tiles of batch b share XCD (b&7).
    gemm_nt_sym_fp8<<<dim3(NTRI * B_DIM), dim3(256), 0, stream>>>((const uint8_t*)metric, out);
}